// Round 9
// baseline (37.744 us; speedup 1.0000x reference)
//
#include <hip/hip_runtime.h>
#include <hip/hip_fp16.h>

#define D_FEAT  128
#define PAD     16      // floats per seg slot = one 64B line per node
#define NCOPY   8       // one seg_sum copy per XCD (blockIdx & 7)

// Dispatch 1: convert feats f32 -> f16 (table becomes 2.56MB -> L2-resident
// per XCD) and zero the used slot of all NCOPY padded seg copies.
__global__ void convert_zero_kernel(const float* __restrict__ feats,
                                    __half* __restrict__ feats16,
                                    float* __restrict__ seg_copies,
                                    int total8, int N) {
    int i = blockIdx.x * blockDim.x + threadIdx.x;
    if (i < NCOPY * N) {
        int c = i / N, n = i - c * N;
        seg_copies[((size_t)c * N + n) * PAD] = 0.0f;
    }
    if (i >= total8) return;
    float4 v0 = ((const float4*)feats)[2 * i];
    float4 v1 = ((const float4*)feats)[2 * i + 1];
    __half2 h[4];
    h[0] = __floats2half2_rn(v0.x, v0.y);
    h[1] = __floats2half2_rn(v0.z, v0.w);
    h[2] = __floats2half2_rn(v1.x, v1.y);
    h[3] = __floats2half2_rn(v1.z, v1.w);
    ((uint4*)feats16)[i] = *reinterpret_cast<uint4*>(h);
}

__device__ inline float l1_u32(unsigned ua, unsigned ub) {
    __half2 ha = *reinterpret_cast<__half2*>(&ua);
    __half2 hb = *reinterpret_cast<__half2*>(&ub);
    float2 fa = __half22float2(ha);
    float2 fb = __half22float2(hb);
    return fabsf(fa.x - fb.x) + fabsf(fa.y - fb.y);
}
__device__ inline float l1_u4(uint4 a, uint4 b) {
    return l1_u32(a.x, b.x) + l1_u32(a.y, b.y)
         + l1_u32(a.z, b.z) + l1_u32(a.w, b.w);
}

// Dispatch 2: 8 lanes per edge. fp16 rows = 256B = 2x uint4 per lane.
// atomicAdd goes to the XCD-local padded copy (blockIdx&7 matches the
// round-robin block->XCD mapping; correctness is mapping-independent).
// seg_max pass dropped: softmax shift invariance, e in (0,1] -> exp(e)<=2.72.
__global__ void edge_eval_kernel(const __half* __restrict__ feats16,
                                 const int* __restrict__ src,
                                 const int* __restrict__ dst,
                                 float* __restrict__ seg_copies,
                                 float* __restrict__ out,
                                 int E, int N) {
    int gtid = blockIdx.x * blockDim.x + threadIdx.x;
    int edge = gtid >> 3;
    int sl   = threadIdx.x & 7;
    if (edge >= E) return;

    int s = src[edge];
    int d = dst[edge];

    const uint4* fa = (const uint4*)(feats16 + (size_t)s * D_FEAT);
    const uint4* fb = (const uint4*)(feats16 + (size_t)d * D_FEAT);
    uint4 a0 = fa[sl];
    uint4 a1 = fa[sl + 8];
    uint4 b0 = fb[sl];
    uint4 b1 = fb[sl + 8];

    float sum = l1_u4(a0, b0) + l1_u4(a1, b1);

    #pragma unroll
    for (int off = 4; off >= 1; off >>= 1)
        sum += __shfl_xor(sum, off, 64);

    if (sl == 0) {
        float p = expf(expf(-0.01f * sum));
        out[edge] = p;
        float* copy = seg_copies + (size_t)(blockIdx.x & (NCOPY - 1)) * N * PAD;
        atomicAdd(copy + (size_t)d * PAD, p);
    }
}

// Dispatch 3: reduce the NCOPY padded copies into compact seg_tot[N].
__global__ void reduce_kernel(const float* __restrict__ seg_copies,
                              float* __restrict__ seg_tot, int N) {
    int i = blockIdx.x * blockDim.x + threadIdx.x;
    if (i >= N) return;
    float s = 0.0f;
    #pragma unroll
    for (int c = 0; c < NCOPY; ++c)
        s += seg_copies[((size_t)c * N + i) * PAD];
    seg_tot[i] = s;
}

// Dispatch 4: out[e] /= seg_tot[dst[e]], 4 edges per thread.
__global__ void edge_div_kernel(const int* __restrict__ dst,
                                const float* __restrict__ seg_tot,
                                float* __restrict__ out,
                                int E4) {
    int i = blockIdx.x * blockDim.x + threadIdx.x;
    if (i >= E4) return;
    float4 p = ((const float4*)out)[i];
    int4   d = ((const int4*)dst)[i];
    p.x /= seg_tot[d.x];
    p.y /= seg_tot[d.y];
    p.z /= seg_tot[d.z];
    p.w /= seg_tot[d.w];
    ((float4*)out)[i] = p;
}

__global__ void edge_div_tail_kernel(const int* __restrict__ dst,
                                     const float* __restrict__ seg_tot,
                                     float* __restrict__ out,
                                     int start, int E) {
    int e = start + blockIdx.x * blockDim.x + threadIdx.x;
    if (e >= E) return;
    out[e] = out[e] / seg_tot[dst[e]];
}

extern "C" void kernel_launch(void* const* d_in, const int* in_sizes, int n_in,
                              void* d_out, int out_size, void* d_ws, size_t ws_size,
                              hipStream_t stream) {
    const float* feats = (const float*)d_in[0];
    const int*   eidx  = (const int*)d_in[1];

    const int E = in_sizes[1] / 2;          // 320000
    const int N = in_sizes[0] / D_FEAT;     // 10000

    const int* src = eidx;       // edge_index row 0
    const int* dst = eidx + E;   // edge_index row 1

    // ws layout (all 16B-aligned):
    float*  seg_copies = (float*)d_ws;                       // NCOPY*N*PAD
    float*  seg_tot    = seg_copies + (size_t)NCOPY * N * PAD; // [N]
    __half* feats16    = (__half*)(seg_tot + ((N + 3) & ~3)); // [N*D]
    float*  out        = (float*)d_out;                      // [E]

    // 1) convert + zero
    {
        int total8 = N * D_FEAT / 8;              // 160000 (> NCOPY*N = 80000)
        int work   = total8 > NCOPY * N ? total8 : NCOPY * N;
        dim3 blk(256);
        dim3 grd((work + 255) / 256);
        convert_zero_kernel<<<grd, blk, 0, stream>>>(feats, feats16,
                                                     seg_copies, total8, N);
    }
    // 2) eval: 8 lanes/edge, 32 edges/block
    {
        dim3 blk(256);
        dim3 grd((E + 31) / 32);
        edge_eval_kernel<<<grd, blk, 0, stream>>>(feats16, src, dst,
                                                  seg_copies, out, E, N);
    }
    // 3) reduce copies -> seg_tot
    {
        dim3 blk(256);
        dim3 grd((N + 255) / 256);
        reduce_kernel<<<grd, blk, 0, stream>>>(seg_copies, seg_tot, N);
    }
    // 4) divide
    {
        int E4 = E >> 2;
        if (E4 > 0) {
            dim3 blk(256);
            dim3 grd((E4 + 255) / 256);
            edge_div_kernel<<<grd, blk, 0, stream>>>(dst, seg_tot, out, E4);
        }
        if (E & 3) {
            int start = E4 << 2;
            edge_div_tail_kernel<<<dim3(1), dim3(64), 0, stream>>>(
                dst, seg_tot, out, start, E);
        }
    }
}

// Round 10
// 34.687 us; speedup vs baseline: 1.0882x; 1.0882x over previous
//
#include <hip/hip_runtime.h>
#include <hip/hip_fp16.h>

#define D_FEAT  128
#define PAD     16      // floats per seg_sum slot = one 64B line per node

// Dispatch 1: convert feats f32 -> f16 and zero the padded seg_sum slots.
// fp16 table = 2.56 MB; replicated across 8 XCD L2s = 20.5 MB < 32 MB
// aggregate, so eval's gathers stay L2-resident (f32 was 41 MB -> thrash).
__global__ void convert_zero_kernel(const float* __restrict__ feats,
                                    __half* __restrict__ feats16,
                                    float* __restrict__ seg_sum,
                                    int total8, int N) {
    int i = blockIdx.x * blockDim.x + threadIdx.x;
    if (i < N) seg_sum[(size_t)i * PAD] = 0.0f;
    if (i >= total8) return;
    float4 v0 = ((const float4*)feats)[2 * i];
    float4 v1 = ((const float4*)feats)[2 * i + 1];
    __half2 h[4];
    h[0] = __floats2half2_rn(v0.x, v0.y);
    h[1] = __floats2half2_rn(v0.z, v0.w);
    h[2] = __floats2half2_rn(v1.x, v1.y);
    h[3] = __floats2half2_rn(v1.z, v1.w);
    ((uint4*)feats16)[i] = *reinterpret_cast<uint4*>(h);
}

__device__ inline float l1_u32(unsigned ua, unsigned ub) {
    __half2 ha = *reinterpret_cast<__half2*>(&ua);
    __half2 hb = *reinterpret_cast<__half2*>(&ub);
    float2 fa = __half22float2(ha);
    float2 fb = __half22float2(hb);
    return fabsf(fa.x - fb.x) + fabsf(fa.y - fb.y);
}
__device__ inline float l1_u4(uint4 a, uint4 b) {
    return l1_u32(a.x, b.x) + l1_u32(a.y, b.y)
         + l1_u32(a.z, b.z) + l1_u32(a.w, b.w);
}

// Dispatch 2: 8 lanes per edge (8 edges per wave64). fp16 row = 256B =
// 2x uint4 per lane (8 lanes x 16B = one 128B line per load instruction).
// seg_sum padded to one 64B line per node (R8's confirmed -6.4us win).
// seg_max pass dropped: softmax is shift-invariant and e = exp(-0.01*L1)
// is in (0,1], so exp(e) <= 2.72 -- no overflow possible.
__global__ void edge_eval_kernel(const __half* __restrict__ feats16,
                                 const int* __restrict__ src,
                                 const int* __restrict__ dst,
                                 float* __restrict__ seg_sum,
                                 float* __restrict__ out,
                                 int E) {
    int gtid = blockIdx.x * blockDim.x + threadIdx.x;
    int edge = gtid >> 3;
    int sl   = threadIdx.x & 7;
    if (edge >= E) return;

    int s = src[edge];
    int d = dst[edge];

    const uint4* fa = (const uint4*)(feats16 + (size_t)s * D_FEAT);
    const uint4* fb = (const uint4*)(feats16 + (size_t)d * D_FEAT);
    uint4 a0 = fa[sl];
    uint4 a1 = fa[sl + 8];
    uint4 b0 = fb[sl];
    uint4 b1 = fb[sl + 8];

    float sum = l1_u4(a0, b0) + l1_u4(a1, b1);

    #pragma unroll
    for (int off = 4; off >= 1; off >>= 1)
        sum += __shfl_xor(sum, off, 64);

    if (sl == 0) {
        float p = expf(expf(-0.01f * sum));
        out[edge] = p;
        atomicAdd(seg_sum + (size_t)d * PAD, p);
    }
}

// Dispatch 3: out[e] /= seg_sum[dst[e]*PAD], 4 edges per thread.
__global__ void edge_div_kernel(const int* __restrict__ dst,
                                const float* __restrict__ seg_sum,
                                float* __restrict__ out,
                                int E4) {
    int i = blockIdx.x * blockDim.x + threadIdx.x;
    if (i >= E4) return;
    float4 p = ((const float4*)out)[i];
    int4   d = ((const int4*)dst)[i];
    p.x /= seg_sum[(size_t)d.x * PAD];
    p.y /= seg_sum[(size_t)d.y * PAD];
    p.z /= seg_sum[(size_t)d.z * PAD];
    p.w /= seg_sum[(size_t)d.w * PAD];
    ((float4*)out)[i] = p;
}

__global__ void edge_div_tail_kernel(const int* __restrict__ dst,
                                     const float* __restrict__ seg_sum,
                                     float* __restrict__ out,
                                     int start, int E) {
    int e = start + blockIdx.x * blockDim.x + threadIdx.x;
    if (e >= E) return;
    out[e] = out[e] / seg_sum[(size_t)dst[e] * PAD];
}

extern "C" void kernel_launch(void* const* d_in, const int* in_sizes, int n_in,
                              void* d_out, int out_size, void* d_ws, size_t ws_size,
                              hipStream_t stream) {
    const float* feats = (const float*)d_in[0];
    const int*   eidx  = (const int*)d_in[1];

    const int E = in_sizes[1] / 2;          // 320000
    const int N = in_sizes[0] / D_FEAT;     // 10000

    const int* src = eidx;       // edge_index row 0
    const int* dst = eidx + E;   // edge_index row 1

    // ws layout (16B-aligned):
    float*  seg_sum = (float*)d_ws;                         // [N*PAD]
    __half* feats16 = (__half*)(seg_sum + (size_t)N * PAD); // [N*D]
    float*  out     = (float*)d_out;                        // [E]

    // 1) convert + zero (one dispatch)
    {
        int total8 = N * D_FEAT / 8;   // 160000 (> N)
        dim3 blk(256);
        dim3 grd((total8 + 255) / 256);
        convert_zero_kernel<<<grd, blk, 0, stream>>>(feats, feats16,
                                                     seg_sum, total8, N);
    }
    // 2) eval: 8 lanes/edge, 32 edges/block
    {
        dim3 blk(256);
        dim3 grd((E + 31) / 32);
        edge_eval_kernel<<<grd, blk, 0, stream>>>(feats16, src, dst,
                                                  seg_sum, out, E);
    }
    // 3) divide: 4 edges/thread
    {
        int E4 = E >> 2;
        if (E4 > 0) {
            dim3 blk(256);
            dim3 grd((E4 + 255) / 256);
            edge_div_kernel<<<grd, blk, 0, stream>>>(dst, seg_sum, out, E4);
        }
        if (E & 3) {
            int start = E4 << 2;
            edge_div_tail_kernel<<<dim3(1), dim3(64), 0, stream>>>(
                dst, seg_sum, out, start, E);
        }
    }
}